// Round 17
// baseline (717.998 us; speedup 1.0000x reference)
//
#include <hip/hip_runtime.h>
#include <math.h>

typedef __attribute__((ext_vector_type(4))) float f32x4;
typedef __attribute__((ext_vector_type(2))) unsigned int u32x2;
typedef __attribute__((ext_vector_type(4))) unsigned int u32x4;
typedef __attribute__((ext_vector_type(8))) unsigned short u16x8;
typedef __attribute__((ext_vector_type(8))) __bf16 bf16x8;
typedef unsigned short ushort_t;

#define H_DIM 2048
#define T_TOK 2048
#define NEXP 16
#define I_DIM 1408
#define I2_DIM 2816
#define IS_DIM 5632
#define MAXROWS 6144

static __device__ __forceinline__ unsigned short f2bf(float f){
  union { float f; unsigned u; } v; v.f = f;
  unsigned r = v.u + 0x7FFFu + ((v.u >> 16) & 1u);
  return (unsigned short)(r >> 16);
}
static __device__ __forceinline__ float bf2f(unsigned short h){
  union { unsigned u; float f; } v; v.u = ((unsigned)h) << 16;
  return v.f;
}
static __device__ __forceinline__ float silu_f(float x){ return x / (1.f + __expf(-x)); }

static __device__ __forceinline__ void gld16(const ushort_t* g, ushort_t* l){
  __builtin_amdgcn_global_load_lds(
      (const __attribute__((address_space(1))) unsigned int*)g,
      (__attribute__((address_space(3))) unsigned int*)l, 16, 0, 0);
}
static __device__ __forceinline__ bf16x8 dsr128(unsigned byte_off){
  u32x4 r;
  asm volatile("ds_read_b128 %0, %1" : "=v"(r) : "v"(byte_off));
  return __builtin_bit_cast(bf16x8, r);
}

// bijective XCD-chunked swizzle over nwg blocks (nwg % 8 == 0 everywhere here)
static __device__ __forceinline__ int swz_r(int nwg, int wgo){
  int q = nwg >> 3, r = nwg & 7;
  int xcd = wgo & 7, idx = wgo >> 3;
  return (xcd < r ? xcd * (q + 1) : r * (q + 1) + (xcd - r) * q) + idx;
}

// inline padded-prefix base for expert e (counts already final)
static __device__ __forceinline__ long base_of(const int* __restrict__ counts, int e){
  long r = 0;
  for (int i = 0; i < e; i++) r += (counts[i] + 127) & ~127;
  return r;
}

// ---------------- transpose tile (128k x 64n); shared passed in ----------------
static __device__ __forceinline__ void tr_tile(float (*tl)[65],
                                               const float* __restrict__ in,
                                               ushort_t* __restrict__ out,
                                               int K, int N, int k0, int n0){
  int t = threadIdx.x;             // 256
  int lr = t >> 4;
  int lc = t & 15;
  #pragma unroll
  for (int p = 0; p < 8; p++){
    int row = p * 16 + lr;
    f32x4 v = *(const f32x4*)&in[(long)(k0 + row) * N + n0 + lc * 4];
    tl[row][lc*4 + 0] = v[0]; tl[row][lc*4 + 1] = v[1];
    tl[row][lc*4 + 2] = v[2]; tl[row][lc*4 + 3] = v[3];
  }
  __syncthreads();
  #pragma unroll
  for (int p = 0; p < 4; p++){
    int n = p * 16 + lr;
    int kc = lc * 8;
    union { ushort_t s[8]; u32x4 v; } pk;
    #pragma unroll
    for (int j = 0; j < 8; j++) pk.s[j] = f2bf(tl[kc + j][n]);
    *(u32x4*)&out[(long)(n0 + n) * K + k0 + kc] = pk.v;
  }
}

// ======== GEMM core v2: 128x128 / BK=32 / 4 waves, 4-buffer depth-3 vmcnt(8), asm ds_read ====
// 64 KiB LDS -> 2 blocks/CU. Tile t's loads issued 3 bodies before use (~3x cadence window).
// emode: 0 bf16 store; 1 masked bf16 store at rbase; 2 atomicAdd scprob scattered; 3 atomicAdd svec.
static __device__ __forceinline__ void gemm_core(
    ushort_t* __restrict__ lds,          // >= 4*8192 elems (64 KiB)
    const ushort_t* __restrict__ Ab, int lda,
    const ushort_t* __restrict__ Bb, int ldbt, int kb,
    int m0, int n0, int cnt, const int* __restrict__ gather, int emode,
    ushort_t* __restrict__ Cb, int ldc, long rbase,
    const int* __restrict__ sclist, const float* __restrict__ scprob,
    const float* __restrict__ svec, float* __restrict__ outp){
  unsigned lbase = (unsigned)(size_t)(__attribute__((address_space(3))) ushort_t*)lds;

  int tid = threadIdx.x;
  int lane = tid & 63;
  int wv = tid >> 6;
  int wm = wv >> 1;
  int wn = wv & 1;

  int srow = lane >> 2;
  int sslot = ((lane & 3) ^ (srow & 3)) * 8;
  long aoff[2], boff[2];
  #pragma unroll
  for (int c = 0; c < 2; c++){
    int mr = wv * 32 + c * 16 + srow;
    int grow;
    if (gather){
      int j = m0 + mr; if (j >= cnt) j = cnt - 1;
      grow = gather[j];
    } else {
      grow = m0 + mr;
    }
    aoff[c] = (long)grow * lda + sslot;
    boff[c] = (long)(n0 + mr) * ldbt + sslot;
  }

  auto stage = [&](int t, int buf){
    long ko = (long)t * 32;
    ushort_t* dA = lds + buf * 8192 + wv * 1024;
    ushort_t* dB = dA + 4096;
    gld16(Ab + aoff[0] + ko, dA);
    gld16(Ab + aoff[1] + ko, dA + 512);
    gld16(Bb + boff[0] + ko, dB);
    gld16(Bb + boff[1] + ko, dB + 512);
  };

  f32x4 zero = {0.f, 0.f, 0.f, 0.f};
  f32x4 acc[4][4];
  #pragma unroll
  for (int i = 0; i < 4; i++)
    #pragma unroll
    for (int j = 0; j < 4; j++) acc[i][j] = zero;

  int fr = lane & 15;
  int kg = lane >> 4;
  unsigned ps = (unsigned)((kg ^ (fr & 3)) << 4);
  unsigned aoffb = (unsigned)((wm * 64 + fr) * 64) + ps;
  unsigned boffb = 8192u + (unsigned)((wn * 64 + fr) * 64) + ps;

  int nt = kb >> 5;
  stage(0, 0);
  __builtin_amdgcn_sched_barrier(0);
  stage(1, 1);
  __builtin_amdgcn_sched_barrier(0);
  if (nt > 2) stage(2, 2);

  for (int t = 0; t < nt; t++){
    // outstanding at top: tiles t..min(t+2, nt-1). Need tile t landed.
    if (t < nt - 2) asm volatile("s_waitcnt vmcnt(8)" ::: "memory");
    else            asm volatile("s_waitcnt vmcnt(0)" ::: "memory");
    __builtin_amdgcn_s_barrier();
    __builtin_amdgcn_sched_barrier(0);
    unsigned bufb = lbase + (unsigned)(t & 3) * 16384u;
    bf16x8 af[4], bg[4];
    #pragma unroll
    for (int f = 0; f < 4; f++){
      af[f] = dsr128(bufb + aoffb + f * 1024u);
      bg[f] = dsr128(bufb + boffb + f * 1024u);
    }
    __builtin_amdgcn_sched_barrier(0);
    if (t + 3 < nt) stage(t + 3, (t + 3) & 3);
    asm volatile("s_waitcnt lgkmcnt(0)" ::: "memory");
    __builtin_amdgcn_sched_barrier(0);
    #pragma unroll
    for (int fm = 0; fm < 4; fm++)
      #pragma unroll
      for (int fn = 0; fn < 4; fn++)
        acc[fm][fn] = __builtin_amdgcn_mfma_f32_16x16x32_bf16(af[fm], bg[fn], acc[fm][fn], 0, 0, 0);
  }

  int colb = n0 + wn * 64 + (lane & 15);
  int rowb = m0 + wm * 64 + (lane >> 4) * 4;
  #pragma unroll
  for (int fm = 0; fm < 4; fm++){
    #pragma unroll
    for (int fn = 0; fn < 4; fn++){
      f32x4 v = acc[fm][fn];
      int col = colb + fn * 16;
      #pragma unroll
      for (int rr = 0; rr < 4; rr++){
        int m = rowb + fm * 16 + rr;
        if (emode == 0){
          Cb[(long)m * ldc + col] = f2bf(v[rr]);
        } else if (emode == 1){
          if (m < cnt) Cb[(rbase + m) * (long)ldc + col] = f2bf(v[rr]);
        } else if (emode == 2){
          if (m < cnt){
            int tok = sclist[m];
            atomicAdd(outp + (long)tok * ldc + col, scprob[m] * v[rr]);
          }
        } else {
          atomicAdd(outp + (long)m * ldc + col, svec[m] * v[rr]);
        }
      }
    }
  }
}

// ---------------- k_tr1: router (0..511) + wsg (512..1919) + wsi (1920..3327) ----------------
__global__ void k_tr1(const float* __restrict__ x, const float* __restrict__ rw,
                      const float* __restrict__ sgw, float* __restrict__ logits,
                      int* __restrict__ counts, int* __restrict__ lists,
                      float* __restrict__ probs, float* __restrict__ sgmul,
                      ushort_t* __restrict__ xb,
                      const float* __restrict__ wsg, const float* __restrict__ wsi,
                      ushort_t* __restrict__ wsg_t, ushort_t* __restrict__ wsi_t){
  __shared__ float tl[128][65];
  int b = blockIdx.x;
  if (b < 512){
    int wid = threadIdx.x >> 6, lane = threadIdx.x & 63;
    int t = b * 4 + wid;
    const float* xr = x + (long)t * H_DIM;
    ushort_t* xbr = xb + (long)t * H_DIM;
    float acc[17];
    #pragma unroll
    for (int e = 0; e < 17; e++) acc[e] = 0.f;
    for (int h0 = lane * 4; h0 < H_DIM; h0 += 256){
      f32x4 xv = *(const f32x4*)&xr[h0];
      u32x2 pk;
      pk[0] = (unsigned)f2bf(xv[0]) | ((unsigned)f2bf(xv[1]) << 16);
      pk[1] = (unsigned)f2bf(xv[2]) | ((unsigned)f2bf(xv[3]) << 16);
      *(u32x2*)&xbr[h0] = pk;
      #pragma unroll
      for (int i = 0; i < 4; i++){
        float xs = xv[i];
        const float* wrow = rw + (long)(h0 + i) * NEXP;
        #pragma unroll
        for (int e = 0; e < 16; e++) acc[e] += xs * wrow[e];
        acc[16] += xs * sgw[h0 + i];
      }
    }
    #pragma unroll
    for (int e = 0; e < 17; e++)
      for (int off = 32; off >= 1; off >>= 1)
        acc[e] += __shfl_xor(acc[e], off);
    if (lane == 0){
      float* lo = logits + (long)t * NEXP;
      #pragma unroll
      for (int e = 0; e < 16; e++) lo[e] = acc[e];
      int e0 = 0;
      #pragma unroll
      for (int e = 1; e < 16; e++) if (acc[e] > acc[e0]) e0 = e;
      int e1 = (e0 == 0) ? 1 : 0;
      #pragma unroll
      for (int e = 0; e < 16; e++) if (e != e0 && acc[e] > acc[e1]) e1 = e;
      float d = acc[e1] - acc[e0];
      float ed = __expf(d);
      float p0 = 1.f / (1.f + ed);
      float p1 = ed / (1.f + ed);
      int pos0 = atomicAdd(&counts[e0], 1);
      lists[e0 * T_TOK + pos0] = t; probs[e0 * T_TOK + pos0] = p0;
      int pos1 = atomicAdd(&counts[e1], 1);
      lists[e1 * T_TOK + pos1] = t; probs[e1 * T_TOK + pos1] = p1;
      sgmul[t] = 1.f / (1.f + __expf(-acc[16]));
    }
    return;
  }
  int bb = b - 512;
  if (bb < 1408){
    int ky = bb / 88, nx = bb % 88;
    tr_tile(tl, wsg, wsg_t, H_DIM, IS_DIM, ky * 128, nx * 64);
  } else {
    int r = bb - 1408;
    int ky = r / 88, nx = r % 88;
    tr_tile(tl, wsi, wsi_t, H_DIM, IS_DIM, ky * 128, nx * 64);
  }
}

// ---- k_gi_tr2: shared gate+inter GEMM (0..1407) + wgu/wout/wso transposes ----
__global__ __launch_bounds__(256) void k_gi_tr2(
    const ushort_t* __restrict__ xb, const ushort_t* __restrict__ wsg_t,
    const ushort_t* __restrict__ wsi_t, ushort_t* __restrict__ sgr,
    const float* __restrict__ wgu, const float* __restrict__ wout,
    const float* __restrict__ wso,
    ushort_t* __restrict__ wgu_t, ushort_t* __restrict__ wout_t,
    ushort_t* __restrict__ wso_t){
  __shared__ char smem[65536];           // union: gemm 64 KiB | tr 33.3 KiB
  int b = blockIdx.x;
  if (b < 1408){
    int z = b & 1;
    int wg = swz_r(704, b >> 1);
    int m0 = (wg % 16) * 128, n0 = (wg / 16) * 128;
    gemm_core((ushort_t*)smem, xb, H_DIM, (z ? wsi_t : wsg_t), H_DIM, H_DIM,
              m0, n0, T_TOK, nullptr, 0,
              sgr + (size_t)z * T_TOK * IS_DIM, IS_DIM, 0,
              nullptr, nullptr, nullptr, nullptr);
    return;
  }
  float (*tl)[65] = (float(*)[65])smem;
  int bb = b - 1408;
  if (bb < 11264){
    int e = bb / 704, r = bb % 704;
    int ky = r / 44, nx = r % 44;
    long zo = (long)e * H_DIM * I2_DIM;
    tr_tile(tl, wgu + zo, wgu_t + zo, H_DIM, I2_DIM, ky * 128, nx * 64);
  } else if (bb < 16896){
    int r = bb - 11264;
    int e = r / 352; r %= 352;
    int ky = r / 32, nx = r % 32;
    long zo = (long)e * I_DIM * H_DIM;
    tr_tile(tl, wout + zo, wout_t + zo, I_DIM, H_DIM, ky * 128, nx * 64);
  } else {
    int r = bb - 16896;
    int ky = r / 32, nx = r % 32;
    tr_tile(tl, wso, wso_t, IS_DIM, H_DIM, ky * 128, nx * 64);
  }
}

// ---- merged: expert gate_up (0..5631) + shared swiglu_flat (5632..11263) ----
__global__ __launch_bounds__(256) void k_gu_flat(
    const ushort_t* __restrict__ xb, const ushort_t* __restrict__ wgu_t,
    ushort_t* __restrict__ gu,
    const int* __restrict__ counts, const int* __restrict__ lists,
    ushort_t* __restrict__ sg, const ushort_t* __restrict__ si){
  int b = blockIdx.x;
  if (b < 5632){
    __shared__ ushort_t lds[4 * 8192];
    int e = b / 352, r = b % 352;
    int wr = swz_r(352, r);
    int m0 = (wr % 16) * 128, n0 = (wr / 16) * 128;
    int cnt = counts[e];
    if (m0 >= cnt) return;
    gemm_core(lds, xb, H_DIM, wgu_t + (size_t)e * I2_DIM * H_DIM, H_DIM, H_DIM,
              m0, n0, cnt, lists + e * T_TOK, 1, gu, I2_DIM, base_of(counts, e),
              nullptr, nullptr, nullptr, nullptr);
  } else {
    long i = ((long)(b - 5632) * 256 + threadIdx.x) * 8;
    u16x8 g = *(const u16x8*)&sg[i];
    u16x8 s = *(const u16x8*)&si[i];
    u16x8 o;
    #pragma unroll
    for (int j = 0; j < 8; j++)
      o[j] = f2bf(bf2f(s[j]) * silu_f(bf2f(g[j])));
    *(u16x8*)&sg[i] = o;
  }
}

// ---- merged: shared out-proj K-split x2 (0..511) + expert swiglu (512..4735) ----
__global__ __launch_bounds__(256) void k_so_se(
    const ushort_t* __restrict__ sgr, const ushort_t* __restrict__ wso_t,
    const float* __restrict__ sgmul, float* __restrict__ out,
    const ushort_t* __restrict__ gu, ushort_t* __restrict__ hid){
  int b = blockIdx.x;
  if (b < 512){
    __shared__ ushort_t lds[4 * 8192];
    int kq = b >> 8, r = b & 255;
    int wr = swz_r(256, r);
    int m0 = (wr % 16) * 128, n0 = (wr / 16) * 128;
    gemm_core(lds, sgr + kq * (IS_DIM/2), IS_DIM, wso_t + kq * (IS_DIM/2), IS_DIM, IS_DIM/2,
              m0, n0, T_TOK, nullptr, 3, nullptr, H_DIM, 0,
              nullptr, nullptr, sgmul, out);
  } else {
    long qd = (long)(b - 512) * 256 + threadIdx.x;
    long r = qd / (I_DIM / 8); int ic = (int)(qd % (I_DIM / 8)) * 8;
    const ushort_t* g = gu + r * I2_DIM + ic;
    u16x8 gv = *(const u16x8*)g;
    u16x8 uv = *(const u16x8*)(g + I_DIM);
    u16x8 ov;
    #pragma unroll
    for (int i = 0; i < 8; i++)
      ov[i] = f2bf(bf2f(uv[i]) * silu_f(bf2f(gv[i])));
    *(u16x8*)&hid[r * I_DIM + ic] = ov;
  }
}

// ---- expert out-projection: 16 experts x 256 blocks ----
__global__ __launch_bounds__(256) void k_eo(
    const ushort_t* __restrict__ hid, const ushort_t* __restrict__ wout_t,
    const int* __restrict__ counts, const int* __restrict__ lists,
    const float* __restrict__ probs, float* __restrict__ out){
  __shared__ ushort_t lds[4 * 8192];
  int b = blockIdx.x;
  int e = b >> 8, r = b & 255;
  int wr = swz_r(256, r);
  int m0 = (wr % 16) * 128, n0 = (wr / 16) * 128;
  int cnt = counts[e];
  if (m0 >= cnt) return;
  gemm_core(lds, hid + (size_t)base_of(counts, e) * I_DIM, I_DIM,
            wout_t + (size_t)e * H_DIM * I_DIM, I_DIM, I_DIM,
            m0, n0, cnt, nullptr, 2, nullptr, H_DIM, 0,
            lists + e * T_TOK, probs + e * T_TOK, nullptr, out);
}

extern "C" void kernel_launch(void* const* d_in, const int* in_sizes, int n_in,
                              void* d_out, int out_size, void* d_ws, size_t ws_size,
                              hipStream_t stream){
  const float* x    = (const float*)d_in[0];
  const float* rw   = (const float*)d_in[1];
  const float* wgu  = (const float*)d_in[2];
  const float* wout = (const float*)d_in[3];
  const float* wsg  = (const float*)d_in[4];
  const float* wsi  = (const float*)d_in[5];
  const float* wso  = (const float*)d_in[6];
  const float* sgw  = (const float*)d_in[7];

  float* out = (float*)d_out;
  float* logits = out + (size_t)T_TOK * H_DIM;

  char* w = (char*)d_ws;
  auto alloc = [&](size_t b){ char* p = w; w += (b + 255) & ~(size_t)255; return p; };
  ushort_t* xb     = (ushort_t*)alloc((size_t)T_TOK * H_DIM * 2);
  ushort_t* wgu_t  = (ushort_t*)alloc((size_t)NEXP * I2_DIM * H_DIM * 2);
  ushort_t* wout_t = (ushort_t*)alloc((size_t)NEXP * H_DIM * I_DIM * 2);
  ushort_t* wsg_t  = (ushort_t*)alloc((size_t)IS_DIM * H_DIM * 2);
  ushort_t* wsi_t  = (ushort_t*)alloc((size_t)IS_DIM * H_DIM * 2);
  ushort_t* wso_t  = (ushort_t*)alloc((size_t)H_DIM * IS_DIM * 2);
  ushort_t* sgr    = (ushort_t*)alloc((size_t)2 * T_TOK * IS_DIM * 2);
  ushort_t* sir    = sgr + (size_t)T_TOK * IS_DIM;
  ushort_t* gu     = (ushort_t*)alloc((size_t)MAXROWS * I2_DIM * 2);
  ushort_t* hid    = (ushort_t*)alloc((size_t)MAXROWS * I_DIM * 2);
  int*   counts = (int*)alloc(64);
  int*   lists  = (int*)alloc((size_t)NEXP * T_TOK * 4);
  float* probs  = (float*)alloc((size_t)NEXP * T_TOK * 4);
  float* sgmul  = (float*)alloc((size_t)T_TOK * 4);

  hipMemsetAsync(counts, 0, 64, stream);
  hipMemsetAsync(out, 0, (size_t)T_TOK * H_DIM * sizeof(float), stream);

  // router + shared gate/inter weight transposes
  k_tr1<<<3328, 256, 0, stream>>>(x, rw, sgw, logits, counts, lists, probs, sgmul, xb,
                                  wsg, wsi, wsg_t, wsi_t);
  // shared gate/inter GEMM (first) + wgu/wout/wso transposes
  k_gi_tr2<<<1408 + 18304, 256, 0, stream>>>(xb, wsg_t, wsi_t, sgr,
                                             wgu, wout, wso, wgu_t, wout_t, wso_t);
  // expert gate_up + shared swiglu
  k_gu_flat<<<5632 + 5632, 256, 0, stream>>>(xb, wgu_t, gu, counts, lists, sgr, sir);
  // shared out-projection (K-split x2) + expert swiglu
  k_so_se<<<512 + 4224, 256, 0, stream>>>(sgr, wso_t, sgmul, out, gu, hid);
  // expert out-projection
  k_eo<<<NEXP * 256, 256, 0, stream>>>(hid, wout_t, counts, lists, probs, out);

  (void)in_sizes; (void)n_in; (void)out_size; (void)ws_size;
}

// Round 18
// 707.714 us; speedup vs baseline: 1.0145x; 1.0145x over previous
//
#include <hip/hip_runtime.h>
#include <math.h>

typedef __attribute__((ext_vector_type(4))) float f32x4;
typedef __attribute__((ext_vector_type(2))) unsigned int u32x2;
typedef __attribute__((ext_vector_type(4))) unsigned int u32x4;
typedef __attribute__((ext_vector_type(8))) unsigned short u16x8;
typedef __attribute__((ext_vector_type(8))) __bf16 bf16x8;
typedef unsigned short ushort_t;

#define H_DIM 2048
#define T_TOK 2048
#define NEXP 16
#define I_DIM 1408
#define I2_DIM 2816
#define IS_DIM 5632
#define MAXROWS 6144

static __device__ __forceinline__ unsigned short f2bf(float f){
  union { float f; unsigned u; } v; v.f = f;
  unsigned r = v.u + 0x7FFFu + ((v.u >> 16) & 1u);
  return (unsigned short)(r >> 16);
}
static __device__ __forceinline__ float bf2f(unsigned short h){
  union { unsigned u; float f; } v; v.u = ((unsigned)h) << 16;
  return v.f;
}
static __device__ __forceinline__ float silu_f(float x){ return x / (1.f + __expf(-x)); }

static __device__ __forceinline__ void gld16(const ushort_t* g, ushort_t* l){
  __builtin_amdgcn_global_load_lds(
      (const __attribute__((address_space(1))) unsigned int*)g,
      (__attribute__((address_space(3))) unsigned int*)l, 16, 0, 0);
}
static __device__ __forceinline__ bf16x8 dsr128(unsigned byte_off){
  u32x4 r;
  asm volatile("ds_read_b128 %0, %1" : "=v"(r) : "v"(byte_off));
  return __builtin_bit_cast(bf16x8, r);
}

// bijective XCD-chunked swizzle over nwg blocks (nwg % 8 == 0 everywhere here)
static __device__ __forceinline__ int swz_r(int nwg, int wgo){
  int q = nwg >> 3, r = nwg & 7;
  int xcd = wgo & 7, idx = wgo >> 3;
  return (xcd < r ? xcd * (q + 1) : r * (q + 1) + (xcd - r) * q) + idx;
}

// inline padded-prefix base for expert e (counts already final)
static __device__ __forceinline__ long base_of(const int* __restrict__ counts, int e){
  long r = 0;
  for (int i = 0; i < e; i++) r += (counts[i] + 127) & ~127;
  return r;
}

// ---------------- transpose tile (128k x 64n); shared passed in ----------------
static __device__ __forceinline__ void tr_tile(float (*tl)[65],
                                               const float* __restrict__ in,
                                               ushort_t* __restrict__ out,
                                               int K, int N, int k0, int n0){
  int t = threadIdx.x;             // 256
  int lr = t >> 4;
  int lc = t & 15;
  #pragma unroll
  for (int p = 0; p < 8; p++){
    int row = p * 16 + lr;
    f32x4 v = *(const f32x4*)&in[(long)(k0 + row) * N + n0 + lc * 4];
    tl[row][lc*4 + 0] = v[0]; tl[row][lc*4 + 1] = v[1];
    tl[row][lc*4 + 2] = v[2]; tl[row][lc*4 + 3] = v[3];
  }
  __syncthreads();
  #pragma unroll
  for (int p = 0; p < 4; p++){
    int n = p * 16 + lr;
    int kc = lc * 8;
    union { ushort_t s[8]; u32x4 v; } pk;
    #pragma unroll
    for (int j = 0; j < 8; j++) pk.s[j] = f2bf(tl[kc + j][n]);
    *(u32x4*)&out[(long)(n0 + n) * K + k0 + kc] = pk.v;
  }
}

// ======== R8 GEMM core: 128x128 / BK=32 / 4 waves, 3-buffer counted-vmcnt, asm ds_read ========
// emode: 0 bf16 store; 1 masked bf16 store at rbase; 2 atomicAdd scprob scattered; 3 atomicAdd svec.
static __device__ __forceinline__ void gemm_core(
    ushort_t* __restrict__ lds,          // >= 3*8192 elems (48 KiB)
    const ushort_t* __restrict__ Ab, int lda,
    const ushort_t* __restrict__ Bb, int ldbt, int kb,
    int m0, int n0, int cnt, const int* __restrict__ gather, int emode,
    ushort_t* __restrict__ Cb, int ldc, long rbase,
    const int* __restrict__ sclist, const float* __restrict__ scprob,
    const float* __restrict__ svec, float* __restrict__ outp){
  unsigned lbase = (unsigned)(size_t)(__attribute__((address_space(3))) ushort_t*)lds;

  int tid = threadIdx.x;
  int lane = tid & 63;
  int wv = tid >> 6;
  int wm = wv >> 1;
  int wn = wv & 1;

  int srow = lane >> 2;
  int sslot = ((lane & 3) ^ (srow & 3)) * 8;
  long aoff[2], boff[2];
  #pragma unroll
  for (int c = 0; c < 2; c++){
    int mr = wv * 32 + c * 16 + srow;
    int grow;
    if (gather){
      int j = m0 + mr; if (j >= cnt) j = cnt - 1;
      grow = gather[j];
    } else {
      grow = m0 + mr;
    }
    aoff[c] = (long)grow * lda + sslot;
    boff[c] = (long)(n0 + mr) * ldbt + sslot;
  }

  auto stage = [&](int t, int buf){
    long ko = (long)t * 32;
    ushort_t* dA = lds + buf * 8192 + wv * 1024;
    ushort_t* dB = dA + 4096;
    gld16(Ab + aoff[0] + ko, dA);
    gld16(Ab + aoff[1] + ko, dA + 512);
    gld16(Bb + boff[0] + ko, dB);
    gld16(Bb + boff[1] + ko, dB + 512);
  };

  f32x4 zero = {0.f, 0.f, 0.f, 0.f};
  f32x4 acc[4][4];
  #pragma unroll
  for (int i = 0; i < 4; i++)
    #pragma unroll
    for (int j = 0; j < 4; j++) acc[i][j] = zero;

  int fr = lane & 15;
  int kg = lane >> 4;
  unsigned ps = (unsigned)((kg ^ (fr & 3)) << 4);
  unsigned aoffb = (unsigned)((wm * 64 + fr) * 64) + ps;
  unsigned boffb = 8192u + (unsigned)((wn * 64 + fr) * 64) + ps;

  int nt = kb >> 5;
  stage(0, 0);
  __builtin_amdgcn_sched_barrier(0);
  stage(1, 1);

  int rb = 0, sb = 2;
  for (int t = 0; t < nt; t++){
    if (t + 2 < nt) asm volatile("s_waitcnt vmcnt(4)" ::: "memory");
    else            asm volatile("s_waitcnt vmcnt(0)" ::: "memory");
    __builtin_amdgcn_s_barrier();
    __builtin_amdgcn_sched_barrier(0);
    unsigned bufb = lbase + (unsigned)rb * 16384u;
    bf16x8 af[4], bg[4];
    #pragma unroll
    for (int f = 0; f < 4; f++){
      af[f] = dsr128(bufb + aoffb + f * 1024u);
      bg[f] = dsr128(bufb + boffb + f * 1024u);
    }
    __builtin_amdgcn_sched_barrier(0);
    if (t + 2 < nt) stage(t + 2, sb);
    asm volatile("s_waitcnt lgkmcnt(0)" ::: "memory");
    __builtin_amdgcn_sched_barrier(0);
    #pragma unroll
    for (int fm = 0; fm < 4; fm++)
      #pragma unroll
      for (int fn = 0; fn < 4; fn++)
        acc[fm][fn] = __builtin_amdgcn_mfma_f32_16x16x32_bf16(af[fm], bg[fn], acc[fm][fn], 0, 0, 0);
    rb = (rb == 2) ? 0 : rb + 1;
    sb = (sb == 2) ? 0 : sb + 1;
  }

  int colb = n0 + wn * 64 + (lane & 15);
  int rowb = m0 + wm * 64 + (lane >> 4) * 4;
  #pragma unroll
  for (int fm = 0; fm < 4; fm++){
    #pragma unroll
    for (int fn = 0; fn < 4; fn++){
      f32x4 v = acc[fm][fn];
      int col = colb + fn * 16;
      #pragma unroll
      for (int rr = 0; rr < 4; rr++){
        int m = rowb + fm * 16 + rr;
        if (emode == 0){
          Cb[(long)m * ldc + col] = f2bf(v[rr]);
        } else if (emode == 1){
          if (m < cnt) Cb[(rbase + m) * (long)ldc + col] = f2bf(v[rr]);
        } else if (emode == 2){
          if (m < cnt){
            int tok = sclist[m];
            atomicAdd(outp + (long)tok * ldc + col, scprob[m] * v[rr]);
          }
        } else {
          atomicAdd(outp + (long)m * ldc + col, svec[m] * v[rr]);
        }
      }
    }
  }
}

// ---------------- k_tr1: router (0..511) + wsg (512..1919) + wsi (1920..3327) + wso (3328..4735) --
__global__ void k_tr1(const float* __restrict__ x, const float* __restrict__ rw,
                      const float* __restrict__ sgw, float* __restrict__ logits,
                      int* __restrict__ counts, int* __restrict__ lists,
                      float* __restrict__ probs, float* __restrict__ sgmul,
                      ushort_t* __restrict__ xb,
                      const float* __restrict__ wsg, const float* __restrict__ wsi,
                      const float* __restrict__ wso,
                      ushort_t* __restrict__ wsg_t, ushort_t* __restrict__ wsi_t,
                      ushort_t* __restrict__ wso_t){
  __shared__ float tl[128][65];
  int b = blockIdx.x;
  if (b < 512){
    int wid = threadIdx.x >> 6, lane = threadIdx.x & 63;
    int t = b * 4 + wid;
    const float* xr = x + (long)t * H_DIM;
    ushort_t* xbr = xb + (long)t * H_DIM;
    float acc[17];
    #pragma unroll
    for (int e = 0; e < 17; e++) acc[e] = 0.f;
    for (int h0 = lane * 4; h0 < H_DIM; h0 += 256){
      f32x4 xv = *(const f32x4*)&xr[h0];
      u32x2 pk;
      pk[0] = (unsigned)f2bf(xv[0]) | ((unsigned)f2bf(xv[1]) << 16);
      pk[1] = (unsigned)f2bf(xv[2]) | ((unsigned)f2bf(xv[3]) << 16);
      *(u32x2*)&xbr[h0] = pk;
      #pragma unroll
      for (int i = 0; i < 4; i++){
        float xs = xv[i];
        const float* wrow = rw + (long)(h0 + i) * NEXP;
        #pragma unroll
        for (int e = 0; e < 16; e++) acc[e] += xs * wrow[e];
        acc[16] += xs * sgw[h0 + i];
      }
    }
    #pragma unroll
    for (int e = 0; e < 17; e++)
      for (int off = 32; off >= 1; off >>= 1)
        acc[e] += __shfl_xor(acc[e], off);
    if (lane == 0){
      float* lo = logits + (long)t * NEXP;
      #pragma unroll
      for (int e = 0; e < 16; e++) lo[e] = acc[e];
      int e0 = 0;
      #pragma unroll
      for (int e = 1; e < 16; e++) if (acc[e] > acc[e0]) e0 = e;
      int e1 = (e0 == 0) ? 1 : 0;
      #pragma unroll
      for (int e = 0; e < 16; e++) if (e != e0 && acc[e] > acc[e1]) e1 = e;
      float d = acc[e1] - acc[e0];
      float ed = __expf(d);
      float p0 = 1.f / (1.f + ed);
      float p1 = ed / (1.f + ed);
      int pos0 = atomicAdd(&counts[e0], 1);
      lists[e0 * T_TOK + pos0] = t; probs[e0 * T_TOK + pos0] = p0;
      int pos1 = atomicAdd(&counts[e1], 1);
      lists[e1 * T_TOK + pos1] = t; probs[e1 * T_TOK + pos1] = p1;
      sgmul[t] = 1.f / (1.f + __expf(-acc[16]));
    }
    return;
  }
  int bb = b - 512;
  if (bb < 1408){
    int ky = bb / 88, nx = bb % 88;
    tr_tile(tl, wsg, wsg_t, H_DIM, IS_DIM, ky * 128, nx * 64);
  } else if (bb < 2816){
    int r = bb - 1408;
    int ky = r / 88, nx = r % 88;
    tr_tile(tl, wsi, wsi_t, H_DIM, IS_DIM, ky * 128, nx * 64);
  } else {
    int r = bb - 2816;
    int ky = r / 32, nx = r % 32;
    tr_tile(tl, wso, wso_t, IS_DIM, H_DIM, ky * 128, nx * 64);
  }
}

// ---- k_gi_tr2: shared gate+inter GEMM (0..1407, dispatched first) + wgu/wout transposes ----
__global__ __launch_bounds__(256) void k_gi_tr2(
    const ushort_t* __restrict__ xb, const ushort_t* __restrict__ wsg_t,
    const ushort_t* __restrict__ wsi_t, ushort_t* __restrict__ sgr,
    const float* __restrict__ wgu, const float* __restrict__ wout,
    ushort_t* __restrict__ wgu_t, ushort_t* __restrict__ wout_t){
  __shared__ char smem[49152];           // union: gemm 48 KiB | tr 33.3 KiB
  int b = blockIdx.x;
  if (b < 1408){
    int z = b & 1;
    int wg = swz_r(704, b >> 1);
    int m0 = (wg % 16) * 128, n0 = (wg / 16) * 128;
    gemm_core((ushort_t*)smem, xb, H_DIM, (z ? wsi_t : wsg_t), H_DIM, H_DIM,
              m0, n0, T_TOK, nullptr, 0,
              sgr + (size_t)z * T_TOK * IS_DIM, IS_DIM, 0,
              nullptr, nullptr, nullptr, nullptr);
    return;
  }
  float (*tl)[65] = (float(*)[65])smem;
  int bb = b - 1408;
  if (bb < 11264){
    int e = bb / 704, r = bb % 704;
    int ky = r / 44, nx = r % 44;
    long zo = (long)e * H_DIM * I2_DIM;
    tr_tile(tl, wgu + zo, wgu_t + zo, H_DIM, I2_DIM, ky * 128, nx * 64);
  } else {
    int r = bb - 11264;
    int e = r / 352; r %= 352;
    int ky = r / 32, nx = r % 32;
    long zo = (long)e * I_DIM * H_DIM;
    tr_tile(tl, wout + zo, wout_t + zo, I_DIM, H_DIM, ky * 128, nx * 64);
  }
}

// ---- merged: expert gate_up (0..5631) + shared swiglu_flat (5632..11263) ----
__global__ __launch_bounds__(256) void k_gu_flat(
    const ushort_t* __restrict__ xb, const ushort_t* __restrict__ wgu_t,
    ushort_t* __restrict__ gu,
    const int* __restrict__ counts, const int* __restrict__ lists,
    ushort_t* __restrict__ sg, const ushort_t* __restrict__ si){
  int b = blockIdx.x;
  if (b < 5632){
    __shared__ ushort_t lds[3 * 8192];
    int e = b / 352, r = b % 352;
    int wr = swz_r(352, r);
    int m0 = (wr % 16) * 128, n0 = (wr / 16) * 128;
    int cnt = counts[e];
    if (m0 >= cnt) return;
    gemm_core(lds, xb, H_DIM, wgu_t + (size_t)e * I2_DIM * H_DIM, H_DIM, H_DIM,
              m0, n0, cnt, lists + e * T_TOK, 1, gu, I2_DIM, base_of(counts, e),
              nullptr, nullptr, nullptr, nullptr);
  } else {
    long i = ((long)(b - 5632) * 256 + threadIdx.x) * 8;
    u16x8 g = *(const u16x8*)&sg[i];
    u16x8 s = *(const u16x8*)&si[i];
    u16x8 o;
    #pragma unroll
    for (int j = 0; j < 8; j++)
      o[j] = f2bf(bf2f(s[j]) * silu_f(bf2f(g[j])));
    *(u16x8*)&sg[i] = o;
  }
}

// ---- merged: shared out-proj K-split x2 (0..511) + expert swiglu (512..4735) ----
__global__ __launch_bounds__(256) void k_so_se(
    const ushort_t* __restrict__ sgr, const ushort_t* __restrict__ wso_t,
    const float* __restrict__ sgmul, float* __restrict__ out,
    const ushort_t* __restrict__ gu, ushort_t* __restrict__ hid){
  int b = blockIdx.x;
  if (b < 512){
    __shared__ ushort_t lds[3 * 8192];
    int kq = b >> 8, r = b & 255;
    int wr = swz_r(256, r);
    int m0 = (wr % 16) * 128, n0 = (wr / 16) * 128;
    gemm_core(lds, sgr + kq * (IS_DIM/2), IS_DIM, wso_t + kq * (IS_DIM/2), IS_DIM, IS_DIM/2,
              m0, n0, T_TOK, nullptr, 3, nullptr, H_DIM, 0,
              nullptr, nullptr, sgmul, out);
  } else {
    long qd = (long)(b - 512) * 256 + threadIdx.x;
    long r = qd / (I_DIM / 8); int ic = (int)(qd % (I_DIM / 8)) * 8;
    const ushort_t* g = gu + r * I2_DIM + ic;
    u16x8 gv = *(const u16x8*)g;
    u16x8 uv = *(const u16x8*)(g + I_DIM);
    u16x8 ov;
    #pragma unroll
    for (int i = 0; i < 8; i++)
      ov[i] = f2bf(bf2f(uv[i]) * silu_f(bf2f(gv[i])));
    *(u16x8*)&hid[r * I_DIM + ic] = ov;
  }
}

// ---- expert out-projection: 16 experts x 256 blocks ----
__global__ __launch_bounds__(256) void k_eo(
    const ushort_t* __restrict__ hid, const ushort_t* __restrict__ wout_t,
    const int* __restrict__ counts, const int* __restrict__ lists,
    const float* __restrict__ probs, float* __restrict__ out){
  __shared__ ushort_t lds[3 * 8192];
  int b = blockIdx.x;
  int e = b >> 8, r = b & 255;
  int wr = swz_r(256, r);
  int m0 = (wr % 16) * 128, n0 = (wr / 16) * 128;
  int cnt = counts[e];
  if (m0 >= cnt) return;
  gemm_core(lds, hid + (size_t)base_of(counts, e) * I_DIM, I_DIM,
            wout_t + (size_t)e * H_DIM * I_DIM, I_DIM, I_DIM,
            m0, n0, cnt, nullptr, 2, nullptr, H_DIM, 0,
            lists + e * T_TOK, probs + e * T_TOK, nullptr, out);
}

extern "C" void kernel_launch(void* const* d_in, const int* in_sizes, int n_in,
                              void* d_out, int out_size, void* d_ws, size_t ws_size,
                              hipStream_t stream){
  const float* x    = (const float*)d_in[0];
  const float* rw   = (const float*)d_in[1];
  const float* wgu  = (const float*)d_in[2];
  const float* wout = (const float*)d_in[3];
  const float* wsg  = (const float*)d_in[4];
  const float* wsi  = (const float*)d_in[5];
  const float* wso  = (const float*)d_in[6];
  const float* sgw  = (const float*)d_in[7];

  float* out = (float*)d_out;
  float* logits = out + (size_t)T_TOK * H_DIM;

  char* w = (char*)d_ws;
  auto alloc = [&](size_t b){ char* p = w; w += (b + 255) & ~(size_t)255; return p; };
  ushort_t* xb     = (ushort_t*)alloc((size_t)T_TOK * H_DIM * 2);
  ushort_t* wgu_t  = (ushort_t*)alloc((size_t)NEXP * I2_DIM * H_DIM * 2);
  ushort_t* wout_t = (ushort_t*)alloc((size_t)NEXP * H_DIM * I_DIM * 2);
  ushort_t* wsg_t  = (ushort_t*)alloc((size_t)IS_DIM * H_DIM * 2);
  ushort_t* wsi_t  = (ushort_t*)alloc((size_t)IS_DIM * H_DIM * 2);
  ushort_t* wso_t  = (ushort_t*)alloc((size_t)H_DIM * IS_DIM * 2);
  ushort_t* sgr    = (ushort_t*)alloc((size_t)2 * T_TOK * IS_DIM * 2);
  ushort_t* sir    = sgr + (size_t)T_TOK * IS_DIM;
  ushort_t* gu     = (ushort_t*)alloc((size_t)MAXROWS * I2_DIM * 2);
  ushort_t* hid    = (ushort_t*)alloc((size_t)MAXROWS * I_DIM * 2);
  int*   counts = (int*)alloc(64);
  int*   lists  = (int*)alloc((size_t)NEXP * T_TOK * 4);
  float* probs  = (float*)alloc((size_t)NEXP * T_TOK * 4);
  float* sgmul  = (float*)alloc((size_t)T_TOK * 4);

  hipMemsetAsync(counts, 0, 64, stream);
  hipMemsetAsync(out, 0, (size_t)T_TOK * H_DIM * sizeof(float), stream);

  // router + shared-path weight transposes
  k_tr1<<<4736, 256, 0, stream>>>(x, rw, sgw, logits, counts, lists, probs, sgmul, xb,
                                  wsg, wsi, wso, wsg_t, wsi_t, wso_t);
  // shared gate/inter GEMM (first) overlapped with expert weight transposes
  k_gi_tr2<<<1408 + 16896, 256, 0, stream>>>(xb, wsg_t, wsi_t, sgr,
                                             wgu, wout, wgu_t, wout_t);
  // expert gate_up + shared swiglu
  k_gu_flat<<<5632 + 5632, 256, 0, stream>>>(xb, wgu_t, gu, counts, lists, sgr, sir);
  // shared out-projection (K-split x2) + expert swiglu
  k_so_se<<<512 + 4224, 256, 0, stream>>>(sgr, wso_t, sgmul, out, gu, hid);
  // expert out-projection
  k_eo<<<NEXP * 256, 256, 0, stream>>>(hid, wout_t, counts, lists, probs, out);

  (void)in_sizes; (void)n_in; (void)out_size; (void)ws_size;
}